// Round 1
// baseline (2441.042 us; speedup 1.0000x reference)
//
#include <hip/hip_runtime.h>

typedef unsigned short u16;
typedef short bfrag __attribute__((ext_vector_type(8)));   // 8 x bf16 (bit pattern)
typedef float ffrag __attribute__((ext_vector_type(4)));   // 4 x f32

#define MFMA_16x16x32(a, b, c) __builtin_amdgcn_mfma_f32_16x16x32_bf16((a), (b), (c), 0, 0, 0)

__device__ __forceinline__ u16 f2b(float f) {
  unsigned u = __float_as_uint(f);
  u += 0x7fffu + ((u >> 16) & 1u);   // RNE
  return (u16)(u >> 16);
}

// XOR swizzles (involutions: selector bits disjoint from flipped bits 4..5 / 4..6)
__device__ __forceinline__ unsigned swz64(unsigned b)  { return b ^ (((b >> 7) & 3u) << 4); }  // 64B rows
__device__ __forceinline__ unsigned swz128(unsigned b) { return b ^ (((b >> 7) & 7u) << 4); }  // 128B rows

// ---------------- embedding + sinusoidal positional encoding ----------------
__global__ __launch_bounds__(256) void embed_kernel(const int* __restrict__ x,
                                                    const float* __restrict__ wtok,
                                                    float* __restrict__ h) {
  int gid = blockIdx.x * 256 + threadIdx.x;     // B*T*512 threads
  int i = gid & 511;
  int t = (gid >> 9) & 1023;
  int b = gid >> 19;
  int id = x[b * 1024 + t];
  float2 tok = *(const float2*)(wtok + (size_t)id * 1024 + 2 * i);  // W_tok[0] is zero row
  float freq = expf(-0.00899447309970f * (float)(2 * i));           // exp(2i * -ln(10000)/1024)
  float ang = (float)t * freq;
  float2 o;
  o.x = tok.x + sinf(ang);
  o.y = tok.y + cosf(ang);
  *(float2*)(h + (size_t)(b * 1024 + t) * 1024 + 2 * i) = o;
}

// ---------------- LayerNorm (fp32 in, bf16 out) ----------------
__global__ __launch_bounds__(256) void ln_kernel(const float* __restrict__ x,
                                                 const float* __restrict__ w,
                                                 const float* __restrict__ bias,
                                                 u16* __restrict__ out) {
  const int row = blockIdx.x, t = threadIdx.x;
  const float* xr = x + (size_t)row * 1024;
  float4 v = *(const float4*)(xr + t * 4);
  float s = v.x + v.y + v.z + v.w;
  float ss = v.x * v.x + v.y * v.y + v.z * v.z + v.w * v.w;
#pragma unroll
  for (int off = 32; off >= 1; off >>= 1) {
    s += __shfl_xor(s, off, 64);
    ss += __shfl_xor(ss, off, 64);
  }
  __shared__ float red[8];
  int wv = t >> 6;
  if ((t & 63) == 0) { red[wv] = s; red[4 + wv] = ss; }
  __syncthreads();
  s = red[0] + red[1] + red[2] + red[3];
  ss = red[4] + red[5] + red[6] + red[7];
  float mu = s * 0.0009765625f;
  float var = ss * 0.0009765625f - mu * mu;
  float rstd = rsqrtf(var + 1e-5f);
  float4 wv4 = *(const float4*)(w + t * 4);
  float4 bv4 = *(const float4*)(bias + t * 4);
  unsigned lo = (unsigned)f2b((v.x - mu) * rstd * wv4.x + bv4.x) |
                ((unsigned)f2b((v.y - mu) * rstd * wv4.y + bv4.y) << 16);
  unsigned hi = (unsigned)f2b((v.z - mu) * rstd * wv4.z + bv4.z) |
                ((unsigned)f2b((v.w - mu) * rstd * wv4.w + bv4.w) << 16);
  uint2 o; o.x = lo; o.y = hi;
  *(uint2*)(out + (size_t)row * 1024 + t * 4) = o;
}

// ---------------- weight transpose: W[K][N] f32 -> WT[N][K] bf16 ----------------
__global__ __launch_bounds__(256) void trans_kernel(const float* __restrict__ W,
                                                    u16* __restrict__ WT, int K, int N) {
  __shared__ u16 tile[32][34];
  const int n0 = blockIdx.x * 32, k0 = blockIdx.y * 32;
  const int t = threadIdx.x, r = t >> 3, c = (t & 7) * 4;
  float4 v = *(const float4*)(W + (size_t)(k0 + r) * N + n0 + c);
  tile[r][c + 0] = f2b(v.x); tile[r][c + 1] = f2b(v.y);
  tile[r][c + 2] = f2b(v.z); tile[r][c + 3] = f2b(v.w);
  __syncthreads();
  unsigned lo = (unsigned)tile[c + 0][r] | ((unsigned)tile[c + 1][r] << 16);
  unsigned hi = (unsigned)tile[c + 2][r] | ((unsigned)tile[c + 3][r] << 16);
  uint2 o; o.x = lo; o.y = hi;
  *(uint2*)(WT + (size_t)(n0 + r) * K + k0 + c) = o;
}

// ---------------- V transpose per layer: qkv v-part [B,T,H,64] -> vT[B,H,64,T] f32 ----------------
__global__ __launch_bounds__(256) void vtrans_kernel(const float* __restrict__ qkv,
                                                     float* __restrict__ vT) {
  __shared__ float tile[32][33];
  const int t0 = blockIdx.x * 32, d0 = blockIdx.y * 32;
  const int bh = blockIdx.z;
  const int b = bh >> 4, hh = bh & 15;
  const int t = threadIdx.x, r = t >> 3, c = (t & 7) * 4;
  const float* src = qkv + (size_t)(b * 1024 + t0 + r) * 3072 + 2048 + hh * 64 + d0 + c;
  float4 v = *(const float4*)src;
  tile[r][c + 0] = v.x; tile[r][c + 1] = v.y; tile[r][c + 2] = v.z; tile[r][c + 3] = v.w;
  __syncthreads();
  float4 o;
  o.x = tile[c + 0][r]; o.y = tile[c + 1][r]; o.z = tile[c + 2][r]; o.w = tile[c + 3][r];
  *(float4*)(vT + (size_t)(bh * 64 + d0 + r) * 1024 + t0 + c) = o;
}

// ---------------- f32 -> bf16 convert ----------------
__global__ __launch_bounds__(256) void tobf_kernel(const float* __restrict__ in,
                                                   u16* __restrict__ out) {
  int g = blockIdx.x * 256 + threadIdx.x;
  float4 v = ((const float4*)in)[g];
  unsigned lo = (unsigned)f2b(v.x) | ((unsigned)f2b(v.y) << 16);
  unsigned hi = (unsigned)f2b(v.z) | ((unsigned)f2b(v.w) << 16);
  uint2 o; o.x = lo; o.y = hi;
  ((uint2*)out)[g] = o;
}

// ---------------- bf16 MFMA GEMM: C[M,N] = A[M,K] @ BT[N,K]^T (+bias, epilogue) ----------------
// EPI: 0 = bias only, 1 = bias+GELU(exact erf), 2 = bias+residual add. OUTB: 1 = bf16 out.
template <int EPI, int OUTB>
__global__ __launch_bounds__(256) void gemm_kernel(const u16* __restrict__ A,
                                                   const u16* __restrict__ BT,
                                                   const float* __restrict__ bias,
                                                   const float* __restrict__ resid,
                                                   void* __restrict__ Cout,
                                                   int M, int N, int K) {
  (void)M;
  __shared__ u16 As[128 * 32];
  __shared__ u16 Bs[128 * 32];
  const int tid = threadIdx.x;
  const int w = tid >> 6, lane = tid & 63;
  const int row0 = blockIdx.y * 128, col0 = blockIdx.x * 128;
  const int sr = tid >> 2;
  const int scb = (tid & 3) * 16;  // byte column offset in the 64B LDS row
  const u16* aP0 = A + (size_t)(row0 + sr) * K + (tid & 3) * 8;
  const u16* aP1 = aP0 + (size_t)64 * K;
  const u16* bP0 = BT + (size_t)(col0 + sr) * K + (tid & 3) * 8;
  const u16* bP1 = bP0 + (size_t)64 * K;
  const unsigned wo0 = swz64(sr * 64 + scb);
  const unsigned wo1 = swz64((sr + 64) * 64 + scb);
  const int wr = w >> 1, wc = w & 1;
  unsigned ao[4], bo[4];
#pragma unroll
  for (int m = 0; m < 4; ++m)
    ao[m] = swz64((wr * 64 + m * 16 + (lane & 15)) * 64 + (lane >> 4) * 16);
#pragma unroll
  for (int n = 0; n < 4; ++n)
    bo[n] = swz64((wc * 64 + n * 16 + (lane & 15)) * 64 + (lane >> 4) * 16);
  ffrag acc[4][4];
#pragma unroll
  for (int m = 0; m < 4; ++m)
#pragma unroll
    for (int n = 0; n < 4; ++n)
#pragma unroll
      for (int r = 0; r < 4; ++r) acc[m][n][r] = 0.f;
  const int nk = K >> 5;
  int4 ga0 = *(const int4*)aP0, ga1 = *(const int4*)aP1;
  int4 gb0 = *(const int4*)bP0, gb1 = *(const int4*)bP1;
  for (int kt = 0;;) {
    __syncthreads();
    *(int4*)((char*)As + wo0) = ga0;
    *(int4*)((char*)As + wo1) = ga1;
    *(int4*)((char*)Bs + wo0) = gb0;
    *(int4*)((char*)Bs + wo1) = gb1;
    const int ktn = kt + 1;
    if (ktn < nk) {
      ga0 = *(const int4*)(aP0 + ktn * 32);
      ga1 = *(const int4*)(aP1 + ktn * 32);
      gb0 = *(const int4*)(bP0 + ktn * 32);
      gb1 = *(const int4*)(bP1 + ktn * 32);
    }
    __syncthreads();
    bfrag af[4], bfv[4];
#pragma unroll
    for (int m = 0; m < 4; ++m) af[m] = *(const bfrag*)((const char*)As + ao[m]);
#pragma unroll
    for (int n = 0; n < 4; ++n) bfv[n] = *(const bfrag*)((const char*)Bs + bo[n]);
#pragma unroll
    for (int m = 0; m < 4; ++m)
#pragma unroll
      for (int n = 0; n < 4; ++n)
        acc[m][n] = MFMA_16x16x32(af[m], bfv[n], acc[m][n]);
    kt = ktn;
    if (kt >= nk) break;
  }
#pragma unroll
  for (int m = 0; m < 4; ++m) {
    const int rl = row0 + wr * 64 + m * 16 + (lane >> 4) * 4;
#pragma unroll
    for (int n = 0; n < 4; ++n) {
      const int cg = col0 + wc * 64 + n * 16 + (lane & 15);
      const float bv = bias ? bias[cg] : 0.f;
#pragma unroll
      for (int r = 0; r < 4; ++r) {
        float vv = acc[m][n][r] + bv;
        size_t idx = (size_t)(rl + r) * N + cg;
        if (EPI == 1) vv = 0.5f * vv * (1.f + erff(vv * 0.70710678118f));
        if (EPI == 2) vv += resid[idx];
        if (OUTB) ((u16*)Cout)[idx] = f2b(vv);
        else ((float*)Cout)[idx] = vv;
      }
    }
  }
}

// ---------------- fused causal flash attention (bf16 MFMA, fp32 softmax) ----------------
// grid: (T/64, H, B); 4 waves, each owns 16 q rows. k-tile = 32.
__global__ __launch_bounds__(256) void attn_kernel(const float* __restrict__ qkv,
                                                   const float* __restrict__ vT,
                                                   u16* __restrict__ o) {
  __shared__ u16 Qs[64 * 64];      // [64 q][64 d], 128B rows, swz128
  __shared__ u16 Ks[32 * 64];      // [32 k][64 d], 128B rows, swz128
  __shared__ u16 Vs[64 * 32];      // V^T tile [64 d][32 k], 64B rows, swz64
  __shared__ u16 Ps[4 * 16 * 32];  // per-wave P [16 q][32 k], 64B rows, swz64
  const int tid = threadIdx.x;
  const int w = tid >> 6, lane = tid & 63;
  const int qt = blockIdx.x, hh = blockIdx.y, b = blockIdx.z;
  const int q0 = qt * 64;
  {  // stage Q, pre-scaled by 1/sqrt(64)
    const int r_ = tid >> 3, c_ = (tid & 7) * 8;
#pragma unroll
    for (int half = 0; half < 2; ++half) {
      int r = r_ + half * 32;
      const float* src = qkv + (size_t)(b * 1024 + q0 + r) * 3072 + hh * 64 + c_;
      float4 f0 = *(const float4*)src;
      float4 f1 = *(const float4*)(src + 4);
      union { bfrag v; u16 u[8]; } pk;
      pk.u[0] = f2b(f0.x * 0.125f); pk.u[1] = f2b(f0.y * 0.125f);
      pk.u[2] = f2b(f0.z * 0.125f); pk.u[3] = f2b(f0.w * 0.125f);
      pk.u[4] = f2b(f1.x * 0.125f); pk.u[5] = f2b(f1.y * 0.125f);
      pk.u[6] = f2b(f1.z * 0.125f); pk.u[7] = f2b(f1.w * 0.125f);
      *(bfrag*)((char*)Qs + swz128(r * 128 + c_ * 2)) = pk.v;
    }
  }
  __syncthreads();
  bfrag qf0 = *(const bfrag*)((const char*)Qs +
               swz128((w * 16 + (lane & 15)) * 128 + (lane >> 4) * 16));
  bfrag qf1 = *(const bfrag*)((const char*)Qs +
               swz128((w * 16 + (lane & 15)) * 128 + 64 + (lane >> 4) * 16));
  float m_r = -1e30f, l_r = 0.f;
  ffrag oa[4];
#pragma unroll
  for (int j = 0; j < 4; ++j)
#pragma unroll
    for (int r = 0; r < 4; ++r) oa[j][r] = 0.f;
  const int ktiles = qt * 2 + 2;
  const int qmax_w = q0 + w * 16 + 15;
  const int qg = q0 + w * 16 + (lane & 15);
  char* pb = (char*)Ps + w * 1024;
  for (int kt = 0; kt < ktiles; ++kt) {
    __syncthreads();
    {  // stage K tile [32][64]
      int r = tid >> 3, c = (tid & 7) * 8;
      const float* src = qkv + (size_t)(b * 1024 + kt * 32 + r) * 3072 + 1024 + hh * 64 + c;
      float4 f0 = *(const float4*)src;
      float4 f1 = *(const float4*)(src + 4);
      union { bfrag v; u16 u[8]; } pk;
      pk.u[0] = f2b(f0.x); pk.u[1] = f2b(f0.y); pk.u[2] = f2b(f0.z); pk.u[3] = f2b(f0.w);
      pk.u[4] = f2b(f1.x); pk.u[5] = f2b(f1.y); pk.u[6] = f2b(f1.z); pk.u[7] = f2b(f1.w);
      *(bfrag*)((char*)Ks + swz128(r * 128 + c * 2)) = pk.v;
    }
    {  // stage V^T tile [64 d][32 k]
      int d = tid >> 2, c = (tid & 3) * 8;
      const float* src = vT + (size_t)((b * 16 + hh) * 64 + d) * 1024 + kt * 32 + c;
      float4 f0 = *(const float4*)src;
      float4 f1 = *(const float4*)(src + 4);
      union { bfrag v; u16 u[8]; } pk;
      pk.u[0] = f2b(f0.x); pk.u[1] = f2b(f0.y); pk.u[2] = f2b(f0.z); pk.u[3] = f2b(f0.w);
      pk.u[4] = f2b(f1.x); pk.u[5] = f2b(f1.y); pk.u[6] = f2b(f1.z); pk.u[7] = f2b(f1.w);
      *(bfrag*)((char*)Vs + swz64(d * 64 + c * 2)) = pk.v;
    }
    __syncthreads();
    if (kt * 32 <= qmax_w) {
      float s[8];
#pragma unroll
      for (int sub = 0; sub < 2; ++sub) {  // S^T = K @ Q^T : rows=k, cols=q
        ffrag sa;
#pragma unroll
        for (int r = 0; r < 4; ++r) sa[r] = 0.f;
        bfrag kf0 = *(const bfrag*)((const char*)Ks +
                     swz128((sub * 16 + (lane & 15)) * 128 + (lane >> 4) * 16));
        bfrag kf1 = *(const bfrag*)((const char*)Ks +
                     swz128((sub * 16 + (lane & 15)) * 128 + 64 + (lane >> 4) * 16));
        sa = MFMA_16x16x32(kf0, qf0, sa);
        sa = MFMA_16x16x32(kf1, qf1, sa);
        s[sub * 4 + 0] = sa[0]; s[sub * 4 + 1] = sa[1];
        s[sub * 4 + 2] = sa[2]; s[sub * 4 + 3] = sa[3];
      }
      float tm = -1e30f;
#pragma unroll
      for (int i = 0; i < 8; ++i) {
        int kg = kt * 32 + (i >> 2) * 16 + (lane >> 4) * 4 + (i & 3);
        if (kg > qg) s[i] = -1e30f;
        tm = fmaxf(tm, s[i]);
      }
      tm = fmaxf(tm, __shfl_xor(tm, 16, 64));
      tm = fmaxf(tm, __shfl_xor(tm, 32, 64));
      float mnew = fmaxf(m_r, tm);
      float corr = __expf(m_r - mnew);
      float p[8], ps = 0.f;
#pragma unroll
      for (int i = 0; i < 8; ++i) { p[i] = __expf(s[i] - mnew); ps += p[i]; }
      ps += __shfl_xor(ps, 16, 64);
      ps += __shfl_xor(ps, 32, 64);
      l_r = l_r * corr + ps;
      m_r = mnew;
#pragma unroll
      for (int i = 0; i < 8; ++i) {  // P^T lane layout -> P row-major in LDS
        int kk = (i >> 2) * 16 + (lane >> 4) * 4 + (i & 3);
        *(u16*)(pb + swz64((lane & 15) * 64 + kk * 2)) = f2b(p[i]);
      }
      float co[4];
#pragma unroll
      for (int r = 0; r < 4; ++r) co[r] = __shfl(corr, 4 * (lane >> 4) + r, 64);
#pragma unroll
      for (int j = 0; j < 4; ++j)
#pragma unroll
        for (int r = 0; r < 4; ++r) oa[j][r] *= co[r];
      bfrag pf = *(const bfrag*)((const char*)pb +
                  swz64((lane & 15) * 64 + (lane >> 4) * 16));
#pragma unroll
      for (int j = 0; j < 4; ++j) {
        bfrag vf = *(const bfrag*)((const char*)Vs +
                    swz64((j * 16 + (lane & 15)) * 64 + (lane >> 4) * 16));
        oa[j] = MFMA_16x16x32(pf, vf, oa[j]);
      }
    }
  }
  float li[4];
#pragma unroll
  for (int r = 0; r < 4; ++r) li[r] = 1.f / __shfl(l_r, 4 * (lane >> 4) + r, 64);
#pragma unroll
  for (int j = 0; j < 4; ++j)
#pragma unroll
    for (int r = 0; r < 4; ++r) {
      int qrow = q0 + w * 16 + 4 * (lane >> 4) + r;
      o[(size_t)(b * 1024 + qrow) * 1024 + hh * 64 + j * 16 + (lane & 15)] =
          f2b(oa[j][r] * li[r]);
    }
}

// ---------------- orchestration ----------------
extern "C" void kernel_launch(void* const* d_in, const int* in_sizes, int n_in,
                              void* d_out, int out_size, void* d_ws, size_t ws_size,
                              hipStream_t stream) {
  (void)in_sizes; (void)n_in; (void)out_size; (void)ws_size;
  const int*   x     = (const int*)d_in[0];
  const float* wtok  = (const float*)d_in[1];
  const float* ln1w  = (const float*)d_in[2];
  const float* ln1b  = (const float*)d_in[3];
  const float* attnw = (const float*)d_in[4];
  const float* attnb = (const float*)d_in[5];
  const float* projw = (const float*)d_in[6];
  const float* projb = (const float*)d_in[7];
  const float* ln2w  = (const float*)d_in[8];
  const float* ln2b  = (const float*)d_in[9];
  const float* ff1w  = (const float*)d_in[10];
  const float* ff1b  = (const float*)d_in[11];
  const float* ff2w  = (const float*)d_in[12];
  const float* ff2b  = (const float*)d_in[13];
  const float* wout  = (const float*)d_in[14];
  float* out = (float*)d_out;
  char* ws = (char*)d_ws;
  constexpr size_t MB = 1024ull * 1024ull;
  float* h     = (float*)(ws + 0);        //  8 MB  residual stream f32 [2048,1024]
  float* qkv   = (float*)(ws + 8 * MB);   // 24 MB  f32 [2048,3072]
  float* vT    = (float*)(ws + 32 * MB);  //  8 MB  f32 [B,H,64,T]
  u16*   ubf   = (u16*)(ws + 40 * MB);    //  4 MB  LN out bf16
  u16*   obf   = (u16*)(ws + 44 * MB);    //  4 MB  attn out bf16
  u16*   actbf = (u16*)(ws + 48 * MB);    // 16 MB  GELU(ff1) bf16 [2048,4096]
  u16*   hbf   = (u16*)(ws + 64 * MB);    //  4 MB  h as bf16
  u16*   wT    = (u16*)(ws + 68 * MB);    // 62.5 MB max transposed weight bf16

  dim3 blk(256);
  embed_kernel<<<4096, blk, 0, stream>>>(x, wtok, h);
  for (int l = 0; l < 8; ++l) {
    ln_kernel<<<2048, blk, 0, stream>>>(h, ln1w + l * 1024, ln1b + l * 1024, ubf);
    trans_kernel<<<dim3(96, 32), blk, 0, stream>>>(attnw + (size_t)l * 1024 * 3072, wT, 1024, 3072);
    gemm_kernel<0, 0><<<dim3(24, 16), blk, 0, stream>>>(ubf, wT, attnb + l * 3072, nullptr, qkv, 2048, 3072, 1024);
    vtrans_kernel<<<dim3(32, 2, 32), blk, 0, stream>>>(qkv, vT);
    attn_kernel<<<dim3(16, 16, 2), blk, 0, stream>>>(qkv, vT, obf);
    trans_kernel<<<dim3(32, 32), blk, 0, stream>>>(projw + (size_t)l * 1024 * 1024, wT, 1024, 1024);
    gemm_kernel<2, 0><<<dim3(8, 16), blk, 0, stream>>>(obf, wT, projb + l * 1024, h, h, 2048, 1024, 1024);
    ln_kernel<<<2048, blk, 0, stream>>>(h, ln2w + l * 1024, ln2b + l * 1024, ubf);
    trans_kernel<<<dim3(128, 32), blk, 0, stream>>>(ff1w + (size_t)l * 1024 * 4096, wT, 1024, 4096);
    gemm_kernel<1, 1><<<dim3(32, 16), blk, 0, stream>>>(ubf, wT, ff1b + l * 4096, nullptr, actbf, 2048, 4096, 1024);
    trans_kernel<<<dim3(32, 128), blk, 0, stream>>>(ff2w + (size_t)l * 4096 * 1024, wT, 4096, 1024);
    gemm_kernel<2, 0><<<dim3(8, 16), blk, 0, stream>>>(actbf, wT, ff2b + l * 1024, h, h, 2048, 1024, 4096);
  }
  tobf_kernel<<<2048, blk, 0, stream>>>(h, hbf);
  trans_kernel<<<dim3(1000, 32), blk, 0, stream>>>(wout, wT, 1024, 32000);
  gemm_kernel<0, 0><<<dim3(250, 16), blk, 0, stream>>>(hbf, wT, nullptr, nullptr, out, 2048, 32000, 1024);
}